// Round 6
// baseline (1019.161 us; speedup 1.0000x reference)
//
#include <hip/hip_runtime.h>
#include <hip/hip_fp16.h>
#include <math.h>

#define N_NODES 100000
#define N_EDGES 1600000
#define EPRIME  (N_EDGES + N_NODES)
#define NEG_SLOPE 0.2f
#define LOG2E 1.44269504f

// ---------------- edge dtype detect (int64 vs int32) ----------------
__global__ __launch_bounds__(256) void detect_k(const unsigned* __restrict__ w,
                                                unsigned* __restrict__ flag) {
    __shared__ int any;
    if (threadIdx.x == 0) any = 0;
    __syncthreads();
    int nz = 0;
    for (int i = threadIdx.x; i < 1024; i += 256)
        if (w[2 * i + 1] != 0u) nz = 1;
    if (nz) atomicOr(&any, 1);
    __syncthreads();
    if (threadIdx.x == 0) flag[0] = any ? 0u : 1u;  // 1 => int64
}

// ---------------- CSR build ----------------
__global__ __launch_bounds__(256) void init_k(int* __restrict__ counts,
                                              int* __restrict__ fill) {
    int n = blockIdx.x * blockDim.x + threadIdx.x;
    if (n < N_NODES) { counts[n] = 1; fill[n] = 0; }  // 1 = self loop
}

__global__ __launch_bounds__(256) void count_k(const int* __restrict__ ei,
                                               const unsigned* __restrict__ flag,
                                               int* __restrict__ counts) {
    int e = blockIdx.x * blockDim.x + threadIdx.x;
    if (e >= N_EDGES) return;
    int d = flag[0] ? ei[2 * (N_EDGES + e)] : ei[N_EDGES + e];
    atomicAdd(&counts[d], 1);
}

// exclusive scan of counts[0..N-1] -> rowptr[0..N], 1024 elems/block
__global__ __launch_bounds__(256) void scan1_k(const int* __restrict__ counts,
                                               int* __restrict__ rowptr,
                                               int* __restrict__ bsums) {
    __shared__ int s[256];
    int t = threadIdx.x;
    int base = blockIdx.x * 1024 + t * 4;
    int v[4];
#pragma unroll
    for (int j = 0; j < 4; ++j)
        v[j] = (base + j < N_NODES) ? counts[base + j] : 0;
    int tsum = v[0] + v[1] + v[2] + v[3];
    s[t] = tsum;
    __syncthreads();
    for (int off = 1; off < 256; off <<= 1) {
        int x = (t >= off) ? s[t - off] : 0;
        __syncthreads();
        s[t] += x;
        __syncthreads();
    }
    if (t == 255) bsums[blockIdx.x] = s[255];
    int run = s[t] - tsum;  // exclusive prefix for this thread (block-local)
#pragma unroll
    for (int j = 0; j < 4; ++j) {
        if (base + j <= N_NODES) rowptr[base + j] = run;
        run += v[j];
    }
}

__global__ void scan2_k(int* __restrict__ bsums, int nb) {
    if (threadIdx.x == 0 && blockIdx.x == 0) {
        int run = 0;
        for (int i = 0; i < nb; ++i) { int c = bsums[i]; bsums[i] = run; run += c; }
    }
}

__global__ __launch_bounds__(256) void scan3_k(int* __restrict__ rowptr,
                                               const int* __restrict__ bsums) {
    int t = threadIdx.x;
    int base = blockIdx.x * 1024 + t * 4;
    int add = bsums[blockIdx.x];
#pragma unroll
    for (int j = 0; j < 4; ++j)
        if (base + j <= N_NODES) rowptr[base + j] += add;
}

__global__ __launch_bounds__(256) void scatter_k(const int* __restrict__ ei,
                                                 const unsigned* __restrict__ flag,
                                                 const int* __restrict__ rowptr,
                                                 int* __restrict__ fill,
                                                 int* __restrict__ col) {
    int t = blockIdx.x * blockDim.x + threadIdx.x;
    if (t >= EPRIME) return;
    int s, d;
    if (t < N_EDGES) {
        if (flag[0]) { s = ei[2 * t]; d = ei[2 * (N_EDGES + t)]; }
        else         { s = ei[t];     d = ei[N_EDGES + t]; }
    } else {
        s = d = t - N_EDGES;
    }
    int pos = rowptr[d] + atomicAdd(&fill[d], 1);
    col[pos] = s;
}

// ---------------- GEMM1: h1 = x @ W1  (N x 512) @ (512 x 64), h1 stored fp16 ---------
// v3: lane = row. Each lane owns one x-row and all 64 output columns in registers.
// Per k: one conflict-free ds_read_b32 feeds 64 FMAs (ratio 64:1 vs old 4:1 —
// old version was LDS-instruction-issue bound at ~250 us). W1[k][c] has no
// thread dependence -> scalar s_load path, SGPR operand in the FMA.
// Epilogue: row-local att-dots (no shuffles), packed fp16 stores.
// v3.1 FIX: h1 row = 64 halves = 128 B = EIGHT float4 stores (was 4 -> half the
// row stayed poison => absmax 0.19).
__global__ __launch_bounds__(256, 4) void gemm1_k(const float* __restrict__ x,
                                                  const float* __restrict__ W1,
                                                  const float* __restrict__ attl,
                                                  const float* __restrict__ attr,
                                                  __half* __restrict__ h1,
                                                  float* __restrict__ ald,
                                                  float* __restrict__ ard) {
    __shared__ float xs[4][64 * 33];  // [wave][row*33+k]; bank=(row+k)%32 -> conflict-free
    int t = threadIdx.x;
    int w = t >> 6, lane = t & 63;
    int row0 = blockIdx.x * 256;
    int myrow = row0 + w * 64 + lane;
    bool valid = myrow < N_NODES;

    float acc[64];
#pragma unroll
    for (int c = 0; c < 64; ++c) acc[c] = 0.f;

    for (int kc = 0; kc < 512; kc += 32) {
        __syncthreads();
        // stage 256 rows x 32 floats (8 float4/thread, coalesced 128B/row segments)
        for (int i = t; i < 2048; i += 256) {
            int r = i >> 3, q = i & 7;
            int gr = row0 + r;
            float4 v = make_float4(0.f, 0.f, 0.f, 0.f);
            if (gr < N_NODES) v = ((const float4*)x)[(size_t)gr * 128 + (kc >> 2) + q];
            float* dst = &xs[r >> 6][(r & 63) * 33 + q * 4];
            dst[0] = v.x; dst[1] = v.y; dst[2] = v.z; dst[3] = v.w;
        }
        __syncthreads();
        const float* xrow = &xs[w][lane * 33];
#pragma unroll 2
        for (int k = 0; k < 32; ++k) {
            float xv = xrow[k];
            const float* wr = &W1[(size_t)(kc + k) * 64];  // uniform -> s_load
#pragma unroll
            for (int c = 0; c < 64; ++c)
                acc[c] = fmaf(xv, wr[c], acc[c]);
        }
    }

    if (valid) {
        // pack to fp16 and store 128B contiguous per lane (8 x dwordx4)
        __half2 hp[32];
#pragma unroll
        for (int c2 = 0; c2 < 32; ++c2)
            hp[c2] = __floats2half2_rn(acc[2 * c2], acc[2 * c2 + 1]);
        const float4* hp4 = (const float4*)hp;
        float4* dsth = (float4*)(h1 + (size_t)myrow * 64);
#pragma unroll
        for (int j = 0; j < 8; ++j) dsth[j] = hp4[j];

        // per-row att dots (attl/attr uniform -> s_load), no cross-lane ops
        float vls[8], vrs[8];
#pragma unroll
        for (int h = 0; h < 8; ++h) {
            float vl = 0.f, vr = 0.f;
#pragma unroll
            for (int cc = 0; cc < 8; ++cc) {
                vl = fmaf(acc[h * 8 + cc], attl[h * 8 + cc], vl);
                vr = fmaf(acc[h * 8 + cc], attr[h * 8 + cc], vr);
            }
            vls[h] = vl * LOG2E;
            vrs[h] = vr * LOG2E;
        }
        float4* dl = (float4*)(ald + (size_t)myrow * 8);
        float4* dr = (float4*)(ard + (size_t)myrow * 8);
        dl[0] = ((const float4*)vls)[0]; dl[1] = ((const float4*)vls)[1];
        dr[0] = ((const float4*)vrs)[0]; dr[1] = ((const float4*)vrs)[1];
    }
}

// ---------------- attn1: one wave per node, lane = channel (64ch, fp16 gathers) -------
// exp2-domain online softmax, defer-max, 2-edge unrolled pipeline (depth-2 prefetch).
__global__ __launch_bounds__(256) void attn1_k(const __half* __restrict__ h1,
                                               const int* __restrict__ rowptr,
                                               const int* __restrict__ col,
                                               const float* __restrict__ ald,
                                               const float* __restrict__ ard,
                                               const float* __restrict__ b1,
                                               float* __restrict__ hout) {
    int wid = (blockIdx.x * blockDim.x + threadIdx.x) >> 6;  // node
    int lane = threadIdx.x & 63;
    if (wid >= N_NODES) return;
    int head = lane >> 3;
    float xi = __half2float(h1[(size_t)wid * 64 + lane]);
    float ardi = ard[wid * 8 + head];
    int beg = rowptr[wid], end = rowptr[wid + 1];
    int last = end - 1;

    // pipeline prime: edges beg, beg+1
    int s0 = col[beg];
    int s1 = col[min(beg + 1, last)];
    float xj0 = __half2float(h1[(size_t)s0 * 64 + lane]);
    float aj0 = ald[s0 * 8 + head];
    float xj1 = __half2float(h1[(size_t)s1 * 64 + lane]);
    float aj1 = ald[s1 * 8 + head];

    float m2 = -INFINITY, lsum = 0.f, accv = 0.f;
    for (int e = beg; e < end; e += 2) {
        // prefetch e+2, e+3 (clamped; harmless dup loads near tail)
        int sp0 = col[min(e + 2, last)];
        int sp1 = col[min(e + 3, last)];
        float xn0 = __half2float(h1[(size_t)sp0 * 64 + lane]);
        float an0 = ald[sp0 * 8 + head];
        float xn1 = __half2float(h1[(size_t)sp1 * 64 + lane]);
        float an1 = ald[sp1 * 8 + head];

        float dot0 = xi * xj0, dot1 = xi * xj1;
        dot0 += __shfl_xor(dot0, 1); dot1 += __shfl_xor(dot1, 1);
        dot0 += __shfl_xor(dot0, 2); dot1 += __shfl_xor(dot1, 2);
        dot0 += __shfl_xor(dot0, 4); dot1 += __shfl_xor(dot1, 4);
        float sig0 = __builtin_amdgcn_rcpf(1.f + __builtin_amdgcn_exp2f(dot0 * -LOG2E));
        float sig1 = __builtin_amdgcn_rcpf(1.f + __builtin_amdgcn_exp2f(dot1 * -LOG2E));
        float g0 = (aj0 + ardi) * sig0;
        float g1 = (aj1 + ardi) * sig1;
        float a20 = fmaxf(g0, NEG_SLOPE * g0);
        float a21 = (e + 1 < end) ? fmaxf(g1, NEG_SLOPE * g1) : -INFINITY;
        float pm = fmaxf(a20, a21);
        if (__any(pm > m2 + 11.5f)) {
            float mn = fmaxf(m2, pm);
            float so = __builtin_amdgcn_exp2f(m2 - mn);
            lsum *= so; accv *= so; m2 = mn;
        }
        float p0 = __builtin_amdgcn_exp2f(a20 - m2);
        float p1 = __builtin_amdgcn_exp2f(a21 - m2);
        lsum += p0 + p1;
        accv += p0 * xj0 + p1 * xj1;
        xj0 = xn0; aj0 = an0; xj1 = xn1; aj1 = an1;
    }
    float o = accv * __builtin_amdgcn_rcpf(lsum) + b1[lane];
    o = o > 0.f ? o : (__builtin_amdgcn_exp2f(o * LOG2E) - 1.f);  // ELU
    hout[(size_t)wid * 64 + lane] = o;
}

// ---------------- GEMM2: h2 = hout @ W2  (N x 64) @ (64 x 128), h2 stored fp16x2 ------
// + fused per-node att dots for layer 2.
__global__ __launch_bounds__(256) void gemm2_k(const float* __restrict__ h,
                                               const float* __restrict__ W2,
                                               const float* __restrict__ attl,
                                               const float* __restrict__ attr,
                                               __half2* __restrict__ h2,
                                               float* __restrict__ ald,
                                               float* __restrict__ ard) {
    __shared__ float xs[32 * 64];
    int t = threadIdx.x;
    int row0 = blockIdx.x * 32;
    for (int i = t; i < 32 * 16; i += 256) {
        int r = i >> 4, q = i & 15;
        int gr = row0 + r;
        float4 v = make_float4(0.f, 0.f, 0.f, 0.f);
        if (gr < N_NODES) v = ((const float4*)h)[(size_t)gr * 16 + q];
        ((float4*)xs)[r * 16 + q] = v;
    }
    __syncthreads();
    int w = t >> 6, lane = t & 63;
    int r0 = w * 8;
    float2 acc[8];
#pragma unroll
    for (int r = 0; r < 8; ++r) acc[r] = make_float2(0.f, 0.f);
    for (int k = 0; k < 64; ++k) {
        float2 wv = ((const float2*)W2)[k * 64 + lane];
#pragma unroll
        for (int r = 0; r < 8; ++r) {
            float xv = xs[(r0 + r) * 64 + k];
            acc[r].x += xv * wv.x;
            acc[r].y += xv * wv.y;
        }
    }
    float2 al = ((const float2*)attl)[lane];
    float2 ar = ((const float2*)attr)[lane];
#pragma unroll
    for (int r = 0; r < 8; ++r) {
        int gr = row0 + r0 + r;
        float vl = acc[r].x * al.x + acc[r].y * al.y;
        float vr = acc[r].x * ar.x + acc[r].y * ar.y;
        vl += __shfl_xor(vl, 1); vr += __shfl_xor(vr, 1);
        vl += __shfl_xor(vl, 2); vr += __shfl_xor(vr, 2);
        vl += __shfl_xor(vl, 4); vr += __shfl_xor(vr, 4);
        if (gr < N_NODES) {
            h2[(size_t)gr * 64 + lane] = __floats2half2_rn(acc[r].x, acc[r].y);
            if ((lane & 7) == 0) {
                ald[gr * 8 + (lane >> 3)] = vl * LOG2E;
                ard[gr * 8 + (lane >> 3)] = vr * LOG2E;
            }
        }
    }
}

// ---------------- attn2: one wave per node, 2 ch/lane (fp16x2 gathers) ----------------
// online softmax (exp2, defer-max), 2-edge pipeline + head mean + bias + log_softmax
__global__ __launch_bounds__(256) void attn2_k(const __half2* __restrict__ h2,
                                               const int* __restrict__ rowptr,
                                               const int* __restrict__ col,
                                               const float* __restrict__ ald,
                                               const float* __restrict__ ard,
                                               const float* __restrict__ b2,
                                               float* __restrict__ out) {
    int wid = (blockIdx.x * blockDim.x + threadIdx.x) >> 6;  // node
    int lane = threadIdx.x & 63;
    if (wid >= N_NODES) return;
    int head = lane >> 3;
    float2 xi = __half22float2(h2[(size_t)wid * 64 + lane]);
    float ardi = ard[wid * 8 + head];
    int beg = rowptr[wid], end = rowptr[wid + 1];
    int last = end - 1;

    int s0 = col[beg];
    int s1 = col[min(beg + 1, last)];
    float2 xj0 = __half22float2(h2[(size_t)s0 * 64 + lane]);
    float aj0 = ald[s0 * 8 + head];
    float2 xj1 = __half22float2(h2[(size_t)s1 * 64 + lane]);
    float aj1 = ald[s1 * 8 + head];

    float m2 = -INFINITY, lsum = 0.f;
    float2 acc = make_float2(0.f, 0.f);
    for (int e = beg; e < end; e += 2) {
        int sp0 = col[min(e + 2, last)];
        int sp1 = col[min(e + 3, last)];
        float2 xn0 = __half22float2(h2[(size_t)sp0 * 64 + lane]);
        float an0 = ald[sp0 * 8 + head];
        float2 xn1 = __half22float2(h2[(size_t)sp1 * 64 + lane]);
        float an1 = ald[sp1 * 8 + head];

        float dot0 = xi.x * xj0.x + xi.y * xj0.y;
        float dot1 = xi.x * xj1.x + xi.y * xj1.y;
        dot0 += __shfl_xor(dot0, 1); dot1 += __shfl_xor(dot1, 1);
        dot0 += __shfl_xor(dot0, 2); dot1 += __shfl_xor(dot1, 2);
        dot0 += __shfl_xor(dot0, 4); dot1 += __shfl_xor(dot1, 4);
        float sig0 = __builtin_amdgcn_rcpf(1.f + __builtin_amdgcn_exp2f(dot0 * -LOG2E));
        float sig1 = __builtin_amdgcn_rcpf(1.f + __builtin_amdgcn_exp2f(dot1 * -LOG2E));
        float g0 = (aj0 + ardi) * sig0;
        float g1 = (aj1 + ardi) * sig1;
        float a20 = fmaxf(g0, NEG_SLOPE * g0);
        float a21 = (e + 1 < end) ? fmaxf(g1, NEG_SLOPE * g1) : -INFINITY;
        float pm = fmaxf(a20, a21);
        if (__any(pm > m2 + 11.5f)) {
            float mn = fmaxf(m2, pm);
            float so = __builtin_amdgcn_exp2f(m2 - mn);
            lsum *= so; acc.x *= so; acc.y *= so; m2 = mn;
        }
        float p0 = __builtin_amdgcn_exp2f(a20 - m2);
        float p1 = __builtin_amdgcn_exp2f(a21 - m2);
        lsum += p0 + p1;
        acc.x += p0 * xj0.x + p1 * xj1.x;
        acc.y += p0 * xj0.y + p1 * xj1.y;
        xj0 = xn0; aj0 = an0; xj1 = xn1; aj1 = an1;
    }
    float rl = __builtin_amdgcn_rcpf(lsum);
    float ox = acc.x * rl;
    float oy = acc.y * rl;
    // mean over heads: lanes with equal (l&7) hold same channel pair across heads
    ox += __shfl_xor(ox, 8); oy += __shfl_xor(oy, 8);
    ox += __shfl_xor(ox, 16); oy += __shfl_xor(oy, 16);
    ox += __shfl_xor(ox, 32); oy += __shfl_xor(oy, 32);
    int c2 = (lane & 7) * 2;
    float vx = ox * 0.125f + b2[c2];
    float vy = oy * 0.125f + b2[c2 + 1];
    // log_softmax across 16 channels held by the 8-lane group (2 per lane)
    float mx = fmaxf(vx, vy);
    mx = fmaxf(mx, __shfl_xor(mx, 1));
    mx = fmaxf(mx, __shfl_xor(mx, 2));
    mx = fmaxf(mx, __shfl_xor(mx, 4));
    float se = __expf(vx - mx) + __expf(vy - mx);
    se += __shfl_xor(se, 1); se += __shfl_xor(se, 2); se += __shfl_xor(se, 4);
    float ls = __logf(se);
    if (lane < 8)
        ((float2*)out)[(size_t)wid * 8 + lane] = make_float2(vx - mx - ls, vy - mx - ls);
}

// ---------------- host ----------------
extern "C" void kernel_launch(void* const* d_in, const int* in_sizes, int n_in,
                              void* d_out, int out_size, void* d_ws, size_t ws_size,
                              hipStream_t stream) {
    const float* x     = (const float*)d_in[0];
    const int*   ei    = (const int*)d_in[1];
    const float* W1    = (const float*)d_in[2];
    const float* attl1 = (const float*)d_in[3];
    const float* attr1 = (const float*)d_in[4];
    const float* b1    = (const float*)d_in[5];
    const float* W2    = (const float*)d_in[6];
    const float* attl2 = (const float*)d_in[7];
    const float* attr2 = (const float*)d_in[8];
    const float* b2    = (const float*)d_in[9];
    float* out = (float*)d_out;

    char* ws = (char*)d_ws;
    size_t off = 0;
    auto alloc = [&](size_t bytes) {
        size_t o = off;
        off += (bytes + 255) & ~(size_t)255;
        return o;
    };
    size_t o_flag   = alloc(4);
    size_t o_counts = alloc((size_t)N_NODES * 4);
    size_t o_fill   = alloc((size_t)N_NODES * 4);
    size_t o_rowptr = alloc((size_t)(N_NODES + 1) * 4);
    size_t o_bsums  = alloc(1024 * 4);
    size_t o_col    = alloc((size_t)EPRIME * 4);
    size_t o_h1     = alloc((size_t)N_NODES * 64 * 4);   // (over-alloc; h1 is fp16 now)
    size_t o_hout   = alloc((size_t)N_NODES * 64 * 4);
    size_t o_h2     = alloc((size_t)N_NODES * 128 * 4);  // (over-alloc; h2 is fp16 now)

    size_t aldsz = ((size_t)N_NODES * 8 * 4 + 255) & ~(size_t)255;
    // layer-1 att dots alias the h2 region (h2 written later, after attn1 reads these)
    size_t o_ald1 = o_h2;
    size_t o_ard1 = o_h2 + aldsz;
    // layer-2 att dots alias the h1 region (h1 dead after attn1)
    size_t o_ald2 = o_h1;
    size_t o_ard2 = o_h1 + aldsz;

    unsigned* flag = (unsigned*)(ws + o_flag);
    int* counts = (int*)(ws + o_counts);
    int* fill   = (int*)(ws + o_fill);
    int* rowptr = (int*)(ws + o_rowptr);
    int* bsums  = (int*)(ws + o_bsums);
    int* col    = (int*)(ws + o_col);
    __half* h1  = (__half*)(ws + o_h1);
    float* hout = (float*)(ws + o_hout);
    __half2* h2 = (__half2*)(ws + o_h2);
    float* ald1 = (float*)(ws + o_ald1);
    float* ard1 = (float*)(ws + o_ard1);
    float* ald2 = (float*)(ws + o_ald2);
    float* ard2 = (float*)(ws + o_ard2);

    int nscan = (N_NODES + 1 + 1023) / 1024;  // 99

    hipLaunchKernelGGL(detect_k, dim3(1), dim3(256), 0, stream, (const unsigned*)ei, flag);
    hipLaunchKernelGGL(init_k, dim3((N_NODES + 255) / 256), dim3(256), 0, stream, counts, fill);
    hipLaunchKernelGGL(count_k, dim3((N_EDGES + 255) / 256), dim3(256), 0, stream, ei, flag, counts);
    hipLaunchKernelGGL(scan1_k, dim3(nscan), dim3(256), 0, stream, counts, rowptr, bsums);
    hipLaunchKernelGGL(scan2_k, dim3(1), dim3(64), 0, stream, bsums, nscan);
    hipLaunchKernelGGL(scan3_k, dim3(nscan), dim3(256), 0, stream, rowptr, bsums);
    hipLaunchKernelGGL(scatter_k, dim3((EPRIME + 255) / 256), dim3(256), 0, stream,
                       ei, flag, rowptr, fill, col);
    hipLaunchKernelGGL(gemm1_k, dim3((N_NODES + 255) / 256), dim3(256), 0, stream,
                       x, W1, attl1, attr1, h1, ald1, ard1);
    hipLaunchKernelGGL(attn1_k, dim3((N_NODES + 3) / 4), dim3(256), 0, stream,
                       h1, rowptr, col, ald1, ard1, b1, hout);
    hipLaunchKernelGGL(gemm2_k, dim3((N_NODES + 31) / 32), dim3(256), 0, stream,
                       hout, W2, attl2, attr2, h2, ald2, ard2);
    hipLaunchKernelGGL(attn2_k, dim3((N_NODES + 3) / 4), dim3(256), 0, stream,
                       h2, rowptr, col, ald2, ard2, b2, out);
}

// Round 7
// 622.379 us; speedup vs baseline: 1.6375x; 1.6375x over previous
//
#include <hip/hip_runtime.h>
#include <hip/hip_fp16.h>
#include <math.h>

#define N_NODES 100000
#define N_EDGES 1600000
#define EPRIME  (N_EDGES + N_NODES)
#define NEG_SLOPE 0.2f
#define LOG2E 1.44269504f

// ---------------- edge dtype detect (int64 vs int32) ----------------
__global__ __launch_bounds__(256) void detect_k(const unsigned* __restrict__ w,
                                                unsigned* __restrict__ flag) {
    __shared__ int any;
    if (threadIdx.x == 0) any = 0;
    __syncthreads();
    int nz = 0;
    for (int i = threadIdx.x; i < 1024; i += 256)
        if (w[2 * i + 1] != 0u) nz = 1;
    if (nz) atomicOr(&any, 1);
    __syncthreads();
    if (threadIdx.x == 0) flag[0] = any ? 0u : 1u;  // 1 => int64
}

// ---------------- CSR build ----------------
__global__ __launch_bounds__(256) void init_k(int* __restrict__ counts,
                                              int* __restrict__ fill) {
    int n = blockIdx.x * blockDim.x + threadIdx.x;
    if (n < N_NODES) { counts[n] = 1; fill[n] = 0; }  // 1 = self loop
}

__global__ __launch_bounds__(256) void count_k(const int* __restrict__ ei,
                                               const unsigned* __restrict__ flag,
                                               int* __restrict__ counts) {
    int e = blockIdx.x * blockDim.x + threadIdx.x;
    if (e >= N_EDGES) return;
    int d = flag[0] ? ei[2 * (N_EDGES + e)] : ei[N_EDGES + e];
    atomicAdd(&counts[d], 1);
}

// exclusive scan of counts[0..N-1] -> rowptr[0..N], 1024 elems/block
__global__ __launch_bounds__(256) void scan1_k(const int* __restrict__ counts,
                                               int* __restrict__ rowptr,
                                               int* __restrict__ bsums) {
    __shared__ int s[256];
    int t = threadIdx.x;
    int base = blockIdx.x * 1024 + t * 4;
    int v[4];
#pragma unroll
    for (int j = 0; j < 4; ++j)
        v[j] = (base + j < N_NODES) ? counts[base + j] : 0;
    int tsum = v[0] + v[1] + v[2] + v[3];
    s[t] = tsum;
    __syncthreads();
    for (int off = 1; off < 256; off <<= 1) {
        int x = (t >= off) ? s[t - off] : 0;
        __syncthreads();
        s[t] += x;
        __syncthreads();
    }
    if (t == 255) bsums[blockIdx.x] = s[255];
    int run = s[t] - tsum;  // exclusive prefix for this thread (block-local)
#pragma unroll
    for (int j = 0; j < 4; ++j) {
        if (base + j <= N_NODES) rowptr[base + j] = run;
        run += v[j];
    }
}

__global__ void scan2_k(int* __restrict__ bsums, int nb) {
    if (threadIdx.x == 0 && blockIdx.x == 0) {
        int run = 0;
        for (int i = 0; i < nb; ++i) { int c = bsums[i]; bsums[i] = run; run += c; }
    }
}

__global__ __launch_bounds__(256) void scan3_k(int* __restrict__ rowptr,
                                               const int* __restrict__ bsums) {
    int t = threadIdx.x;
    int base = blockIdx.x * 1024 + t * 4;
    int add = bsums[blockIdx.x];
#pragma unroll
    for (int j = 0; j < 4; ++j)
        if (base + j <= N_NODES) rowptr[base + j] += add;
}

__global__ __launch_bounds__(256) void scatter_k(const int* __restrict__ ei,
                                                 const unsigned* __restrict__ flag,
                                                 const int* __restrict__ rowptr,
                                                 int* __restrict__ fill,
                                                 int* __restrict__ col) {
    int t = blockIdx.x * blockDim.x + threadIdx.x;
    if (t >= EPRIME) return;
    int s, d;
    if (t < N_EDGES) {
        if (flag[0]) { s = ei[2 * t]; d = ei[2 * (N_EDGES + t)]; }
        else         { s = ei[t];     d = ei[N_EDGES + t]; }
    } else {
        s = d = t - N_EDGES;
    }
    int pos = rowptr[d] + atomicAdd(&fill[d], 1);
    col[pos] = s;
}

// ---------------- GEMM1: h1 = x @ W1  (N x 512) @ (512 x 64), h1 stored fp16 ---------
// v4: lane = row, COLUMN-SPLIT across wave pairs. R5's acc[64] + launch_bounds(256,4)
// cap of 128 VGPR made the allocator spill the whole accumulator to scratch
// (VGPR_Count=52, VALUBusy 6%). Now each lane owns 32 columns: acc[32]+temps ~80
// VGPR fits the cap with no spill. c0 via readfirstlane keeps W1 addressing
// wave-uniform -> s_load scalar path. 1 ds_read_b32 feeds 32 FMAs, conflict-free.
__global__ __launch_bounds__(256, 4) void gemm1_k(const float* __restrict__ x,
                                                  const float* __restrict__ W1,
                                                  const float* __restrict__ attl,
                                                  const float* __restrict__ attr,
                                                  __half* __restrict__ h1,
                                                  float* __restrict__ ald,
                                                  float* __restrict__ ard) {
    __shared__ float xs[128 * 33];  // 16.9 KB; bank=(row+k)%32 -> 2-way max (free)
    int t = threadIdx.x;
    int w = t >> 6, lane = t & 63;
    int row0 = blockIdx.x * 128;
    int rsub = (w & 1) * 64;
    int c0 = __builtin_amdgcn_readfirstlane((w >> 1) * 32);  // 0 or 32, wave-uniform
    int myrow = row0 + rsub + lane;
    bool valid = myrow < N_NODES;

    float acc[32];
#pragma unroll
    for (int c = 0; c < 32; ++c) acc[c] = 0.f;

    for (int kc = 0; kc < 512; kc += 32) {
        __syncthreads();
        // stage 128 rows x 32 floats (4 float4/thread, coalesced)
        for (int i = t; i < 1024; i += 256) {
            int r = i >> 3, q = i & 7;
            int gr = row0 + r;
            float4 v = make_float4(0.f, 0.f, 0.f, 0.f);
            if (gr < N_NODES) v = ((const float4*)x)[(size_t)gr * 128 + (kc >> 2) + q];
            float* dst = &xs[r * 33 + q * 4];
            dst[0] = v.x; dst[1] = v.y; dst[2] = v.z; dst[3] = v.w;
        }
        __syncthreads();
        const float* xrow = &xs[(rsub + lane) * 33];
#pragma unroll 4
        for (int k = 0; k < 32; ++k) {
            float xv = xrow[k];
            const float* wr = &W1[(size_t)(kc + k) * 64 + c0];  // uniform -> s_load
#pragma unroll
            for (int c = 0; c < 32; ++c)
                acc[c] = fmaf(xv, wr[c], acc[c]);
        }
    }

    if (valid) {
        // pack 32 cols to fp16: 64 B = 4 x dwordx4
        __half2 hp[16];
#pragma unroll
        for (int c2 = 0; c2 < 16; ++c2)
            hp[c2] = __floats2half2_rn(acc[2 * c2], acc[2 * c2 + 1]);
        const float4* hp4 = (const float4*)hp;
        float4* dsth = (float4*)(h1 + (size_t)myrow * 64 + c0);
#pragma unroll
        for (int j = 0; j < 4; ++j) dsth[j] = hp4[j];

        // att dots for this half's 4 heads (row-local, no shuffles)
        float vls[4], vrs[4];
#pragma unroll
        for (int h = 0; h < 4; ++h) {
            float vl = 0.f, vr = 0.f;
#pragma unroll
            for (int cc = 0; cc < 8; ++cc) {
                vl = fmaf(acc[h * 8 + cc], attl[c0 + h * 8 + cc], vl);
                vr = fmaf(acc[h * 8 + cc], attr[c0 + h * 8 + cc], vr);
            }
            vls[h] = vl * LOG2E;
            vrs[h] = vr * LOG2E;
        }
        *(float4*)(ald + (size_t)myrow * 8 + (c0 >> 3)) = ((const float4*)vls)[0];
        *(float4*)(ard + (size_t)myrow * 8 + (c0 >> 3)) = ((const float4*)vrs)[0];
    }
}

// ---------------- attn1: one wave per node, lane = channel (64ch, fp16 gathers) -------
// exp2-domain online softmax, defer-max, 2-edge unrolled pipeline (depth-2 prefetch).
__global__ __launch_bounds__(256) void attn1_k(const __half* __restrict__ h1,
                                               const int* __restrict__ rowptr,
                                               const int* __restrict__ col,
                                               const float* __restrict__ ald,
                                               const float* __restrict__ ard,
                                               const float* __restrict__ b1,
                                               float* __restrict__ hout) {
    int wid = (blockIdx.x * blockDim.x + threadIdx.x) >> 6;  // node
    int lane = threadIdx.x & 63;
    if (wid >= N_NODES) return;
    int head = lane >> 3;
    float xi = __half2float(h1[(size_t)wid * 64 + lane]);
    float ardi = ard[wid * 8 + head];
    int beg = rowptr[wid], end = rowptr[wid + 1];
    int last = end - 1;

    // pipeline prime: edges beg, beg+1
    int s0 = col[beg];
    int s1 = col[min(beg + 1, last)];
    float xj0 = __half2float(h1[(size_t)s0 * 64 + lane]);
    float aj0 = ald[s0 * 8 + head];
    float xj1 = __half2float(h1[(size_t)s1 * 64 + lane]);
    float aj1 = ald[s1 * 8 + head];

    float m2 = -INFINITY, lsum = 0.f, accv = 0.f;
    for (int e = beg; e < end; e += 2) {
        // prefetch e+2, e+3 (clamped; harmless dup loads near tail)
        int sp0 = col[min(e + 2, last)];
        int sp1 = col[min(e + 3, last)];
        float xn0 = __half2float(h1[(size_t)sp0 * 64 + lane]);
        float an0 = ald[sp0 * 8 + head];
        float xn1 = __half2float(h1[(size_t)sp1 * 64 + lane]);
        float an1 = ald[sp1 * 8 + head];

        float dot0 = xi * xj0, dot1 = xi * xj1;
        dot0 += __shfl_xor(dot0, 1); dot1 += __shfl_xor(dot1, 1);
        dot0 += __shfl_xor(dot0, 2); dot1 += __shfl_xor(dot1, 2);
        dot0 += __shfl_xor(dot0, 4); dot1 += __shfl_xor(dot1, 4);
        float sig0 = __builtin_amdgcn_rcpf(1.f + __builtin_amdgcn_exp2f(dot0 * -LOG2E));
        float sig1 = __builtin_amdgcn_rcpf(1.f + __builtin_amdgcn_exp2f(dot1 * -LOG2E));
        float g0 = (aj0 + ardi) * sig0;
        float g1 = (aj1 + ardi) * sig1;
        float a20 = fmaxf(g0, NEG_SLOPE * g0);
        float a21 = (e + 1 < end) ? fmaxf(g1, NEG_SLOPE * g1) : -INFINITY;
        float pm = fmaxf(a20, a21);
        if (__any(pm > m2 + 11.5f)) {
            float mn = fmaxf(m2, pm);
            float so = __builtin_amdgcn_exp2f(m2 - mn);
            lsum *= so; accv *= so; m2 = mn;
        }
        float p0 = __builtin_amdgcn_exp2f(a20 - m2);
        float p1 = __builtin_amdgcn_exp2f(a21 - m2);
        lsum += p0 + p1;
        accv += p0 * xj0 + p1 * xj1;
        xj0 = xn0; aj0 = an0; xj1 = xn1; aj1 = an1;
    }
    float o = accv * __builtin_amdgcn_rcpf(lsum) + b1[lane];
    o = o > 0.f ? o : (__builtin_amdgcn_exp2f(o * LOG2E) - 1.f);  // ELU
    hout[(size_t)wid * 64 + lane] = o;
}

// ---------------- GEMM2: h2 = hout @ W2  (N x 64) @ (64 x 128), h2 stored fp16x2 ------
// + fused per-node att dots for layer 2.
__global__ __launch_bounds__(256) void gemm2_k(const float* __restrict__ h,
                                               const float* __restrict__ W2,
                                               const float* __restrict__ attl,
                                               const float* __restrict__ attr,
                                               __half2* __restrict__ h2,
                                               float* __restrict__ ald,
                                               float* __restrict__ ard) {
    __shared__ float xs[32 * 64];
    int t = threadIdx.x;
    int row0 = blockIdx.x * 32;
    for (int i = t; i < 32 * 16; i += 256) {
        int r = i >> 4, q = i & 15;
        int gr = row0 + r;
        float4 v = make_float4(0.f, 0.f, 0.f, 0.f);
        if (gr < N_NODES) v = ((const float4*)h)[(size_t)gr * 16 + q];
        ((float4*)xs)[r * 16 + q] = v;
    }
    __syncthreads();
    int w = t >> 6, lane = t & 63;
    int r0 = w * 8;
    float2 acc[8];
#pragma unroll
    for (int r = 0; r < 8; ++r) acc[r] = make_float2(0.f, 0.f);
    for (int k = 0; k < 64; ++k) {
        float2 wv = ((const float2*)W2)[k * 64 + lane];
#pragma unroll
        for (int r = 0; r < 8; ++r) {
            float xv = xs[(r0 + r) * 64 + k];
            acc[r].x += xv * wv.x;
            acc[r].y += xv * wv.y;
        }
    }
    float2 al = ((const float2*)attl)[lane];
    float2 ar = ((const float2*)attr)[lane];
#pragma unroll
    for (int r = 0; r < 8; ++r) {
        int gr = row0 + r0 + r;
        float vl = acc[r].x * al.x + acc[r].y * al.y;
        float vr = acc[r].x * ar.x + acc[r].y * ar.y;
        vl += __shfl_xor(vl, 1); vr += __shfl_xor(vr, 1);
        vl += __shfl_xor(vl, 2); vr += __shfl_xor(vr, 2);
        vl += __shfl_xor(vl, 4); vr += __shfl_xor(vr, 4);
        if (gr < N_NODES) {
            h2[(size_t)gr * 64 + lane] = __floats2half2_rn(acc[r].x, acc[r].y);
            if ((lane & 7) == 0) {
                ald[gr * 8 + (lane >> 3)] = vl * LOG2E;
                ard[gr * 8 + (lane >> 3)] = vr * LOG2E;
            }
        }
    }
}

// ---------------- attn2: one wave per node, 2 ch/lane (fp16x2 gathers) ----------------
// online softmax (exp2, defer-max), 2-edge pipeline + head mean + bias + log_softmax
__global__ __launch_bounds__(256) void attn2_k(const __half2* __restrict__ h2,
                                               const int* __restrict__ rowptr,
                                               const int* __restrict__ col,
                                               const float* __restrict__ ald,
                                               const float* __restrict__ ard,
                                               const float* __restrict__ b2,
                                               float* __restrict__ out) {
    int wid = (blockIdx.x * blockDim.x + threadIdx.x) >> 6;  // node
    int lane = threadIdx.x & 63;
    if (wid >= N_NODES) return;
    int head = lane >> 3;
    float2 xi = __half22float2(h2[(size_t)wid * 64 + lane]);
    float ardi = ard[wid * 8 + head];
    int beg = rowptr[wid], end = rowptr[wid + 1];
    int last = end - 1;

    int s0 = col[beg];
    int s1 = col[min(beg + 1, last)];
    float2 xj0 = __half22float2(h2[(size_t)s0 * 64 + lane]);
    float aj0 = ald[s0 * 8 + head];
    float2 xj1 = __half22float2(h2[(size_t)s1 * 64 + lane]);
    float aj1 = ald[s1 * 8 + head];

    float m2 = -INFINITY, lsum = 0.f;
    float2 acc = make_float2(0.f, 0.f);
    for (int e = beg; e < end; e += 2) {
        int sp0 = col[min(e + 2, last)];
        int sp1 = col[min(e + 3, last)];
        float2 xn0 = __half22float2(h2[(size_t)sp0 * 64 + lane]);
        float an0 = ald[sp0 * 8 + head];
        float2 xn1 = __half22float2(h2[(size_t)sp1 * 64 + lane]);
        float an1 = ald[sp1 * 8 + head];

        float dot0 = xi.x * xj0.x + xi.y * xj0.y;
        float dot1 = xi.x * xj1.x + xi.y * xj1.y;
        dot0 += __shfl_xor(dot0, 1); dot1 += __shfl_xor(dot1, 1);
        dot0 += __shfl_xor(dot0, 2); dot1 += __shfl_xor(dot1, 2);
        dot0 += __shfl_xor(dot0, 4); dot1 += __shfl_xor(dot1, 4);
        float sig0 = __builtin_amdgcn_rcpf(1.f + __builtin_amdgcn_exp2f(dot0 * -LOG2E));
        float sig1 = __builtin_amdgcn_rcpf(1.f + __builtin_amdgcn_exp2f(dot1 * -LOG2E));
        float g0 = (aj0 + ardi) * sig0;
        float g1 = (aj1 + ardi) * sig1;
        float a20 = fmaxf(g0, NEG_SLOPE * g0);
        float a21 = (e + 1 < end) ? fmaxf(g1, NEG_SLOPE * g1) : -INFINITY;
        float pm = fmaxf(a20, a21);
        if (__any(pm > m2 + 11.5f)) {
            float mn = fmaxf(m2, pm);
            float so = __builtin_amdgcn_exp2f(m2 - mn);
            lsum *= so; acc.x *= so; acc.y *= so; m2 = mn;
        }
        float p0 = __builtin_amdgcn_exp2f(a20 - m2);
        float p1 = __builtin_amdgcn_exp2f(a21 - m2);
        lsum += p0 + p1;
        acc.x += p0 * xj0.x + p1 * xj1.x;
        acc.y += p0 * xj0.y + p1 * xj1.y;
        xj0 = xn0; aj0 = an0; xj1 = xn1; aj1 = an1;
    }
    float rl = __builtin_amdgcn_rcpf(lsum);
    float ox = acc.x * rl;
    float oy = acc.y * rl;
    // mean over heads: lanes with equal (l&7) hold same channel pair across heads
    ox += __shfl_xor(ox, 8); oy += __shfl_xor(oy, 8);
    ox += __shfl_xor(ox, 16); oy += __shfl_xor(oy, 16);
    ox += __shfl_xor(ox, 32); oy += __shfl_xor(oy, 32);
    int c2 = (lane & 7) * 2;
    float vx = ox * 0.125f + b2[c2];
    float vy = oy * 0.125f + b2[c2 + 1];
    // log_softmax across 16 channels held by the 8-lane group (2 per lane)
    float mx = fmaxf(vx, vy);
    mx = fmaxf(mx, __shfl_xor(mx, 1));
    mx = fmaxf(mx, __shfl_xor(mx, 2));
    mx = fmaxf(mx, __shfl_xor(mx, 4));
    float se = __expf(vx - mx) + __expf(vy - mx);
    se += __shfl_xor(se, 1); se += __shfl_xor(se, 2); se += __shfl_xor(se, 4);
    float ls = __logf(se);
    if (lane < 8)
        ((float2*)out)[(size_t)wid * 8 + lane] = make_float2(vx - mx - ls, vy - mx - ls);
}

// ---------------- host ----------------
extern "C" void kernel_launch(void* const* d_in, const int* in_sizes, int n_in,
                              void* d_out, int out_size, void* d_ws, size_t ws_size,
                              hipStream_t stream) {
    const float* x     = (const float*)d_in[0];
    const int*   ei    = (const int*)d_in[1];
    const float* W1    = (const float*)d_in[2];
    const float* attl1 = (const float*)d_in[3];
    const float* attr1 = (const float*)d_in[4];
    const float* b1    = (const float*)d_in[5];
    const float* W2    = (const float*)d_in[6];
    const float* attl2 = (const float*)d_in[7];
    const float* attr2 = (const float*)d_in[8];
    const float* b2    = (const float*)d_in[9];
    float* out = (float*)d_out;

    char* ws = (char*)d_ws;
    size_t off = 0;
    auto alloc = [&](size_t bytes) {
        size_t o = off;
        off += (bytes + 255) & ~(size_t)255;
        return o;
    };
    size_t o_flag   = alloc(4);
    size_t o_counts = alloc((size_t)N_NODES * 4);
    size_t o_fill   = alloc((size_t)N_NODES * 4);
    size_t o_rowptr = alloc((size_t)(N_NODES + 1) * 4);
    size_t o_bsums  = alloc(1024 * 4);
    size_t o_col    = alloc((size_t)EPRIME * 4);
    size_t o_h1     = alloc((size_t)N_NODES * 64 * 4);   // (over-alloc; h1 is fp16 now)
    size_t o_hout   = alloc((size_t)N_NODES * 64 * 4);
    size_t o_h2     = alloc((size_t)N_NODES * 128 * 4);  // (over-alloc; h2 is fp16 now)

    size_t aldsz = ((size_t)N_NODES * 8 * 4 + 255) & ~(size_t)255;
    // layer-1 att dots alias the h2 region (h2 written later, after attn1 reads these)
    size_t o_ald1 = o_h2;
    size_t o_ard1 = o_h2 + aldsz;
    // layer-2 att dots alias the h1 region (h1 dead after attn1)
    size_t o_ald2 = o_h1;
    size_t o_ard2 = o_h1 + aldsz;

    unsigned* flag = (unsigned*)(ws + o_flag);
    int* counts = (int*)(ws + o_counts);
    int* fill   = (int*)(ws + o_fill);
    int* rowptr = (int*)(ws + o_rowptr);
    int* bsums  = (int*)(ws + o_bsums);
    int* col    = (int*)(ws + o_col);
    __half* h1  = (__half*)(ws + o_h1);
    float* hout = (float*)(ws + o_hout);
    __half2* h2 = (__half2*)(ws + o_h2);
    float* ald1 = (float*)(ws + o_ald1);
    float* ard1 = (float*)(ws + o_ard1);
    float* ald2 = (float*)(ws + o_ald2);
    float* ard2 = (float*)(ws + o_ard2);

    int nscan = (N_NODES + 1 + 1023) / 1024;  // 99

    hipLaunchKernelGGL(detect_k, dim3(1), dim3(256), 0, stream, (const unsigned*)ei, flag);
    hipLaunchKernelGGL(init_k, dim3((N_NODES + 255) / 256), dim3(256), 0, stream, counts, fill);
    hipLaunchKernelGGL(count_k, dim3((N_EDGES + 255) / 256), dim3(256), 0, stream, ei, flag, counts);
    hipLaunchKernelGGL(scan1_k, dim3(nscan), dim3(256), 0, stream, counts, rowptr, bsums);
    hipLaunchKernelGGL(scan2_k, dim3(1), dim3(64), 0, stream, bsums, nscan);
    hipLaunchKernelGGL(scan3_k, dim3(nscan), dim3(256), 0, stream, rowptr, bsums);
    hipLaunchKernelGGL(scatter_k, dim3((EPRIME + 255) / 256), dim3(256), 0, stream,
                       ei, flag, rowptr, fill, col);
    hipLaunchKernelGGL(gemm1_k, dim3((N_NODES + 127) / 128), dim3(256), 0, stream,
                       x, W1, attl1, attr1, h1, ald1, ard1);
    hipLaunchKernelGGL(attn1_k, dim3((N_NODES + 3) / 4), dim3(256), 0, stream,
                       h1, rowptr, col, ald1, ard1, b1, hout);
    hipLaunchKernelGGL(gemm2_k, dim3((N_NODES + 31) / 32), dim3(256), 0, stream,
                       hout, W2, attl2, attr2, h2, ald2, ard2);
    hipLaunchKernelGGL(attn2_k, dim3((N_NODES + 3) / 4), dim3(256), 0, stream,
                       h2, rowptr, col, ald2, ard2, b2, out);
}

// Round 8
// 613.400 us; speedup vs baseline: 1.6615x; 1.0146x over previous
//
#include <hip/hip_runtime.h>
#include <hip/hip_fp16.h>
#include <math.h>

#define N_NODES 100000
#define N_EDGES 1600000
#define EPRIME  (N_EDGES + N_NODES)
#define NEG_SLOPE 0.2f
#define LOG2E 1.44269504f

// ---------------- edge dtype detect (int64 vs int32) ----------------
__global__ __launch_bounds__(256) void detect_k(const unsigned* __restrict__ w,
                                                unsigned* __restrict__ flag) {
    __shared__ int any;
    if (threadIdx.x == 0) any = 0;
    __syncthreads();
    int nz = 0;
    for (int i = threadIdx.x; i < 1024; i += 256)
        if (w[2 * i + 1] != 0u) nz = 1;
    if (nz) atomicOr(&any, 1);
    __syncthreads();
    if (threadIdx.x == 0) flag[0] = any ? 0u : 1u;  // 1 => int64
}

// ---------------- CSR build ----------------
__global__ __launch_bounds__(256) void init_k(int* __restrict__ counts,
                                              int* __restrict__ fill) {
    int n = blockIdx.x * blockDim.x + threadIdx.x;
    if (n < N_NODES) { counts[n] = 1; fill[n] = 0; }  // 1 = self loop
}

__global__ __launch_bounds__(256) void count_k(const int* __restrict__ ei,
                                               const unsigned* __restrict__ flag,
                                               int* __restrict__ counts) {
    int e = blockIdx.x * blockDim.x + threadIdx.x;
    if (e >= N_EDGES) return;
    int d = flag[0] ? ei[2 * (N_EDGES + e)] : ei[N_EDGES + e];
    atomicAdd(&counts[d], 1);
}

// exclusive scan of counts[0..N-1] -> rowptr[0..N], 1024 elems/block
__global__ __launch_bounds__(256) void scan1_k(const int* __restrict__ counts,
                                               int* __restrict__ rowptr,
                                               int* __restrict__ bsums) {
    __shared__ int s[256];
    int t = threadIdx.x;
    int base = blockIdx.x * 1024 + t * 4;
    int v[4];
#pragma unroll
    for (int j = 0; j < 4; ++j)
        v[j] = (base + j < N_NODES) ? counts[base + j] : 0;
    int tsum = v[0] + v[1] + v[2] + v[3];
    s[t] = tsum;
    __syncthreads();
    for (int off = 1; off < 256; off <<= 1) {
        int x = (t >= off) ? s[t - off] : 0;
        __syncthreads();
        s[t] += x;
        __syncthreads();
    }
    if (t == 255) bsums[blockIdx.x] = s[255];
    int run = s[t] - tsum;  // exclusive prefix for this thread (block-local)
#pragma unroll
    for (int j = 0; j < 4; ++j) {
        if (base + j <= N_NODES) rowptr[base + j] = run;
        run += v[j];
    }
}

__global__ void scan2_k(int* __restrict__ bsums, int nb) {
    if (threadIdx.x == 0 && blockIdx.x == 0) {
        int run = 0;
        for (int i = 0; i < nb; ++i) { int c = bsums[i]; bsums[i] = run; run += c; }
    }
}

__global__ __launch_bounds__(256) void scan3_k(int* __restrict__ rowptr,
                                               const int* __restrict__ bsums) {
    int t = threadIdx.x;
    int base = blockIdx.x * 1024 + t * 4;
    int add = bsums[blockIdx.x];
#pragma unroll
    for (int j = 0; j < 4; ++j)
        if (base + j <= N_NODES) rowptr[base + j] += add;
}

__global__ __launch_bounds__(256) void scatter_k(const int* __restrict__ ei,
                                                 const unsigned* __restrict__ flag,
                                                 const int* __restrict__ rowptr,
                                                 int* __restrict__ fill,
                                                 int* __restrict__ col) {
    int t = blockIdx.x * blockDim.x + threadIdx.x;
    if (t >= EPRIME) return;
    int s, d;
    if (t < N_EDGES) {
        if (flag[0]) { s = ei[2 * t]; d = ei[2 * (N_EDGES + t)]; }
        else         { s = ei[t];     d = ei[N_EDGES + t]; }
    } else {
        s = d = t - N_EDGES;
    }
    int pos = rowptr[d] + atomicAdd(&fill[d], 1);
    col[pos] = s;
}

// ---------------- GEMM1: h1 = x @ W1  (N x 512) @ (512 x 64), h1 stored fp16 ---------
// v5: lane = row, 16 cols/wave. R5 (acc[64]) and R6 (acc[32]) both spilled the
// accumulator to scratch (VGPR_Count 52 / 28 < array size): SGPR overflow from
// deep-unrolled s_load pipelining cascaded into VGPR eviction. v5 shrinks ALL
// state: acc[16], unroll 2 (<=8 s_load_dwordx4 in flight = 32 SGPR), no
// launch_bounds cap, no address-taken local arrays in the epilogue.
__global__ __launch_bounds__(256) void gemm1_k(const float* __restrict__ x,
                                               const float* __restrict__ W1,
                                               const float* __restrict__ attl,
                                               const float* __restrict__ attr,
                                               __half* __restrict__ h1,
                                               float* __restrict__ ald,
                                               float* __restrict__ ard) {
    __shared__ float xs[64 * 33];  // 8.4 KB; bank=(row+k)%32 -> 2-way max (free)
    int t = threadIdx.x;
    int w = t >> 6, lane = t & 63;
    int c0 = __builtin_amdgcn_readfirstlane(w * 16);  // wave-uniform col base
    int row0 = blockIdx.x * 64;
    int myrow = row0 + lane;
    bool valid = myrow < N_NODES;

    float acc[16];
#pragma unroll
    for (int c = 0; c < 16; ++c) acc[c] = 0.f;

    for (int kc = 0; kc < 512; kc += 32) {
        __syncthreads();
        // stage 64 rows x 32 k (512 float4, 2 per thread, coalesced)
        for (int i = t; i < 512; i += 256) {
            int r = i >> 3, q = i & 7;
            int gr = row0 + r;
            float4 v = make_float4(0.f, 0.f, 0.f, 0.f);
            if (gr < N_NODES) v = ((const float4*)x)[(size_t)gr * 128 + (kc >> 2) + q];
            float* dst = &xs[r * 33 + q * 4];
            dst[0] = v.x; dst[1] = v.y; dst[2] = v.z; dst[3] = v.w;
        }
        __syncthreads();
        const float* xrow = &xs[lane * 33];
#pragma unroll 2
        for (int k = 0; k < 32; ++k) {
            float xv = xrow[k];
            const float* wr = &W1[(size_t)(kc + k) * 64 + c0];  // uniform -> s_load
#pragma unroll
            for (int c = 0; c < 16; ++c)
                acc[c] = fmaf(xv, wr[c], acc[c]);
        }
    }

    if (valid) {
        // pack 16 cols to fp16 (32 B) without address-taking any local array
        unsigned u0 = __builtin_bit_cast(unsigned, __floats2half2_rn(acc[0],  acc[1]));
        unsigned u1 = __builtin_bit_cast(unsigned, __floats2half2_rn(acc[2],  acc[3]));
        unsigned u2 = __builtin_bit_cast(unsigned, __floats2half2_rn(acc[4],  acc[5]));
        unsigned u3 = __builtin_bit_cast(unsigned, __floats2half2_rn(acc[6],  acc[7]));
        unsigned u4 = __builtin_bit_cast(unsigned, __floats2half2_rn(acc[8],  acc[9]));
        unsigned u5 = __builtin_bit_cast(unsigned, __floats2half2_rn(acc[10], acc[11]));
        unsigned u6 = __builtin_bit_cast(unsigned, __floats2half2_rn(acc[12], acc[13]));
        unsigned u7 = __builtin_bit_cast(unsigned, __floats2half2_rn(acc[14], acc[15]));
        float4* dst = (float4*)(h1 + (size_t)myrow * 64 + c0);
        dst[0] = make_float4(__uint_as_float(u0), __uint_as_float(u1),
                             __uint_as_float(u2), __uint_as_float(u3));
        dst[1] = make_float4(__uint_as_float(u4), __uint_as_float(u5),
                             __uint_as_float(u6), __uint_as_float(u7));

        // att dots for this wave's 2 heads (row-local, scalar stores)
#pragma unroll
        for (int h = 0; h < 2; ++h) {
            float vl = 0.f, vr = 0.f;
#pragma unroll
            for (int cc = 0; cc < 8; ++cc) {
                vl = fmaf(acc[h * 8 + cc], attl[c0 + h * 8 + cc], vl);
                vr = fmaf(acc[h * 8 + cc], attr[c0 + h * 8 + cc], vr);
            }
            ald[(size_t)myrow * 8 + (c0 >> 3) + h] = vl * LOG2E;
            ard[(size_t)myrow * 8 + (c0 >> 3) + h] = vr * LOG2E;
        }
    }
}

// ---------------- attn1: one wave per node, lane = channel (64ch, fp16 gathers) -------
// exp2-domain online softmax, defer-max, 2-edge unrolled pipeline (depth-2 prefetch).
__global__ __launch_bounds__(256) void attn1_k(const __half* __restrict__ h1,
                                               const int* __restrict__ rowptr,
                                               const int* __restrict__ col,
                                               const float* __restrict__ ald,
                                               const float* __restrict__ ard,
                                               const float* __restrict__ b1,
                                               float* __restrict__ hout) {
    int wid = (blockIdx.x * blockDim.x + threadIdx.x) >> 6;  // node
    int lane = threadIdx.x & 63;
    if (wid >= N_NODES) return;
    int head = lane >> 3;
    float xi = __half2float(h1[(size_t)wid * 64 + lane]);
    float ardi = ard[wid * 8 + head];
    int beg = rowptr[wid], end = rowptr[wid + 1];
    int last = end - 1;

    // pipeline prime: edges beg, beg+1
    int s0 = col[beg];
    int s1 = col[min(beg + 1, last)];
    float xj0 = __half2float(h1[(size_t)s0 * 64 + lane]);
    float aj0 = ald[s0 * 8 + head];
    float xj1 = __half2float(h1[(size_t)s1 * 64 + lane]);
    float aj1 = ald[s1 * 8 + head];

    float m2 = -INFINITY, lsum = 0.f, accv = 0.f;
    for (int e = beg; e < end; e += 2) {
        // prefetch e+2, e+3 (clamped; harmless dup loads near tail)
        int sp0 = col[min(e + 2, last)];
        int sp1 = col[min(e + 3, last)];
        float xn0 = __half2float(h1[(size_t)sp0 * 64 + lane]);
        float an0 = ald[sp0 * 8 + head];
        float xn1 = __half2float(h1[(size_t)sp1 * 64 + lane]);
        float an1 = ald[sp1 * 8 + head];

        float dot0 = xi * xj0, dot1 = xi * xj1;
        dot0 += __shfl_xor(dot0, 1); dot1 += __shfl_xor(dot1, 1);
        dot0 += __shfl_xor(dot0, 2); dot1 += __shfl_xor(dot1, 2);
        dot0 += __shfl_xor(dot0, 4); dot1 += __shfl_xor(dot1, 4);
        float sig0 = __builtin_amdgcn_rcpf(1.f + __builtin_amdgcn_exp2f(dot0 * -LOG2E));
        float sig1 = __builtin_amdgcn_rcpf(1.f + __builtin_amdgcn_exp2f(dot1 * -LOG2E));
        float g0 = (aj0 + ardi) * sig0;
        float g1 = (aj1 + ardi) * sig1;
        float a20 = fmaxf(g0, NEG_SLOPE * g0);
        float a21 = (e + 1 < end) ? fmaxf(g1, NEG_SLOPE * g1) : -INFINITY;
        float pm = fmaxf(a20, a21);
        if (__any(pm > m2 + 11.5f)) {
            float mn = fmaxf(m2, pm);
            float so = __builtin_amdgcn_exp2f(m2 - mn);
            lsum *= so; accv *= so; m2 = mn;
        }
        float p0 = __builtin_amdgcn_exp2f(a20 - m2);
        float p1 = __builtin_amdgcn_exp2f(a21 - m2);
        lsum += p0 + p1;
        accv += p0 * xj0 + p1 * xj1;
        xj0 = xn0; aj0 = an0; xj1 = xn1; aj1 = an1;
    }
    float o = accv * __builtin_amdgcn_rcpf(lsum) + b1[lane];
    o = o > 0.f ? o : (__builtin_amdgcn_exp2f(o * LOG2E) - 1.f);  // ELU
    hout[(size_t)wid * 64 + lane] = o;
}

// ---------------- GEMM2: h2 = hout @ W2  (N x 64) @ (64 x 128), h2 stored fp16x2 ------
// + fused per-node att dots for layer 2.
__global__ __launch_bounds__(256) void gemm2_k(const float* __restrict__ h,
                                               const float* __restrict__ W2,
                                               const float* __restrict__ attl,
                                               const float* __restrict__ attr,
                                               __half2* __restrict__ h2,
                                               float* __restrict__ ald,
                                               float* __restrict__ ard) {
    __shared__ float xs[32 * 64];
    int t = threadIdx.x;
    int row0 = blockIdx.x * 32;
    for (int i = t; i < 32 * 16; i += 256) {
        int r = i >> 4, q = i & 15;
        int gr = row0 + r;
        float4 v = make_float4(0.f, 0.f, 0.f, 0.f);
        if (gr < N_NODES) v = ((const float4*)h)[(size_t)gr * 16 + q];
        ((float4*)xs)[r * 16 + q] = v;
    }
    __syncthreads();
    int w = t >> 6, lane = t & 63;
    int r0 = w * 8;
    float2 acc[8];
#pragma unroll
    for (int r = 0; r < 8; ++r) acc[r] = make_float2(0.f, 0.f);
    for (int k = 0; k < 64; ++k) {
        float2 wv = ((const float2*)W2)[k * 64 + lane];
#pragma unroll
        for (int r = 0; r < 8; ++r) {
            float xv = xs[(r0 + r) * 64 + k];
            acc[r].x += xv * wv.x;
            acc[r].y += xv * wv.y;
        }
    }
    float2 al = ((const float2*)attl)[lane];
    float2 ar = ((const float2*)attr)[lane];
#pragma unroll
    for (int r = 0; r < 8; ++r) {
        int gr = row0 + r0 + r;
        float vl = acc[r].x * al.x + acc[r].y * al.y;
        float vr = acc[r].x * ar.x + acc[r].y * ar.y;
        vl += __shfl_xor(vl, 1); vr += __shfl_xor(vr, 1);
        vl += __shfl_xor(vl, 2); vr += __shfl_xor(vr, 2);
        vl += __shfl_xor(vl, 4); vr += __shfl_xor(vr, 4);
        if (gr < N_NODES) {
            h2[(size_t)gr * 64 + lane] = __floats2half2_rn(acc[r].x, acc[r].y);
            if ((lane & 7) == 0) {
                ald[gr * 8 + (lane >> 3)] = vl * LOG2E;
                ard[gr * 8 + (lane >> 3)] = vr * LOG2E;
            }
        }
    }
}

// ---------------- attn2: one wave per node, 2 ch/lane (fp16x2 gathers) ----------------
// online softmax (exp2, defer-max), 2-edge pipeline + head mean + bias + log_softmax
__global__ __launch_bounds__(256) void attn2_k(const __half2* __restrict__ h2,
                                               const int* __restrict__ rowptr,
                                               const int* __restrict__ col,
                                               const float* __restrict__ ald,
                                               const float* __restrict__ ard,
                                               const float* __restrict__ b2,
                                               float* __restrict__ out) {
    int wid = (blockIdx.x * blockDim.x + threadIdx.x) >> 6;  // node
    int lane = threadIdx.x & 63;
    if (wid >= N_NODES) return;
    int head = lane >> 3;
    float2 xi = __half22float2(h2[(size_t)wid * 64 + lane]);
    float ardi = ard[wid * 8 + head];
    int beg = rowptr[wid], end = rowptr[wid + 1];
    int last = end - 1;

    int s0 = col[beg];
    int s1 = col[min(beg + 1, last)];
    float2 xj0 = __half22float2(h2[(size_t)s0 * 64 + lane]);
    float aj0 = ald[s0 * 8 + head];
    float2 xj1 = __half22float2(h2[(size_t)s1 * 64 + lane]);
    float aj1 = ald[s1 * 8 + head];

    float m2 = -INFINITY, lsum = 0.f;
    float2 acc = make_float2(0.f, 0.f);
    for (int e = beg; e < end; e += 2) {
        int sp0 = col[min(e + 2, last)];
        int sp1 = col[min(e + 3, last)];
        float2 xn0 = __half22float2(h2[(size_t)sp0 * 64 + lane]);
        float an0 = ald[sp0 * 8 + head];
        float2 xn1 = __half22float2(h2[(size_t)sp1 * 64 + lane]);
        float an1 = ald[sp1 * 8 + head];

        float dot0 = xi.x * xj0.x + xi.y * xj0.y;
        float dot1 = xi.x * xj1.x + xi.y * xj1.y;
        dot0 += __shfl_xor(dot0, 1); dot1 += __shfl_xor(dot1, 1);
        dot0 += __shfl_xor(dot0, 2); dot1 += __shfl_xor(dot1, 2);
        dot0 += __shfl_xor(dot0, 4); dot1 += __shfl_xor(dot1, 4);
        float sig0 = __builtin_amdgcn_rcpf(1.f + __builtin_amdgcn_exp2f(dot0 * -LOG2E));
        float sig1 = __builtin_amdgcn_rcpf(1.f + __builtin_amdgcn_exp2f(dot1 * -LOG2E));
        float g0 = (aj0 + ardi) * sig0;
        float g1 = (aj1 + ardi) * sig1;
        float a20 = fmaxf(g0, NEG_SLOPE * g0);
        float a21 = (e + 1 < end) ? fmaxf(g1, NEG_SLOPE * g1) : -INFINITY;
        float pm = fmaxf(a20, a21);
        if (__any(pm > m2 + 11.5f)) {
            float mn = fmaxf(m2, pm);
            float so = __builtin_amdgcn_exp2f(m2 - mn);
            lsum *= so; acc.x *= so; acc.y *= so; m2 = mn;
        }
        float p0 = __builtin_amdgcn_exp2f(a20 - m2);
        float p1 = __builtin_amdgcn_exp2f(a21 - m2);
        lsum += p0 + p1;
        acc.x += p0 * xj0.x + p1 * xj1.x;
        acc.y += p0 * xj0.y + p1 * xj1.y;
        xj0 = xn0; aj0 = an0; xj1 = xn1; aj1 = an1;
    }
    float rl = __builtin_amdgcn_rcpf(lsum);
    float ox = acc.x * rl;
    float oy = acc.y * rl;
    // mean over heads: lanes with equal (l&7) hold same channel pair across heads
    ox += __shfl_xor(ox, 8); oy += __shfl_xor(oy, 8);
    ox += __shfl_xor(ox, 16); oy += __shfl_xor(oy, 16);
    ox += __shfl_xor(ox, 32); oy += __shfl_xor(oy, 32);
    int c2 = (lane & 7) * 2;
    float vx = ox * 0.125f + b2[c2];
    float vy = oy * 0.125f + b2[c2 + 1];
    // log_softmax across 16 channels held by the 8-lane group (2 per lane)
    float mx = fmaxf(vx, vy);
    mx = fmaxf(mx, __shfl_xor(mx, 1));
    mx = fmaxf(mx, __shfl_xor(mx, 2));
    mx = fmaxf(mx, __shfl_xor(mx, 4));
    float se = __expf(vx - mx) + __expf(vy - mx);
    se += __shfl_xor(se, 1); se += __shfl_xor(se, 2); se += __shfl_xor(se, 4);
    float ls = __logf(se);
    if (lane < 8)
        ((float2*)out)[(size_t)wid * 8 + lane] = make_float2(vx - mx - ls, vy - mx - ls);
}

// ---------------- host ----------------
extern "C" void kernel_launch(void* const* d_in, const int* in_sizes, int n_in,
                              void* d_out, int out_size, void* d_ws, size_t ws_size,
                              hipStream_t stream) {
    const float* x     = (const float*)d_in[0];
    const int*   ei    = (const int*)d_in[1];
    const float* W1    = (const float*)d_in[2];
    const float* attl1 = (const float*)d_in[3];
    const float* attr1 = (const float*)d_in[4];
    const float* b1    = (const float*)d_in[5];
    const float* W2    = (const float*)d_in[6];
    const float* attl2 = (const float*)d_in[7];
    const float* attr2 = (const float*)d_in[8];
    const float* b2    = (const float*)d_in[9];
    float* out = (float*)d_out;

    char* ws = (char*)d_ws;
    size_t off = 0;
    auto alloc = [&](size_t bytes) {
        size_t o = off;
        off += (bytes + 255) & ~(size_t)255;
        return o;
    };
    size_t o_flag   = alloc(4);
    size_t o_counts = alloc((size_t)N_NODES * 4);
    size_t o_fill   = alloc((size_t)N_NODES * 4);
    size_t o_rowptr = alloc((size_t)(N_NODES + 1) * 4);
    size_t o_bsums  = alloc(1024 * 4);
    size_t o_col    = alloc((size_t)EPRIME * 4);
    size_t o_h1     = alloc((size_t)N_NODES * 64 * 4);   // (over-alloc; h1 is fp16 now)
    size_t o_hout   = alloc((size_t)N_NODES * 64 * 4);
    size_t o_h2     = alloc((size_t)N_NODES * 128 * 4);  // (over-alloc; h2 is fp16 now)

    size_t aldsz = ((size_t)N_NODES * 8 * 4 + 255) & ~(size_t)255;
    // layer-1 att dots alias the h2 region (h2 written later, after attn1 reads these)
    size_t o_ald1 = o_h2;
    size_t o_ard1 = o_h2 + aldsz;
    // layer-2 att dots alias the h1 region (h1 dead after attn1)
    size_t o_ald2 = o_h1;
    size_t o_ard2 = o_h1 + aldsz;

    unsigned* flag = (unsigned*)(ws + o_flag);
    int* counts = (int*)(ws + o_counts);
    int* fill   = (int*)(ws + o_fill);
    int* rowptr = (int*)(ws + o_rowptr);
    int* bsums  = (int*)(ws + o_bsums);
    int* col    = (int*)(ws + o_col);
    __half* h1  = (__half*)(ws + o_h1);
    float* hout = (float*)(ws + o_hout);
    __half2* h2 = (__half2*)(ws + o_h2);
    float* ald1 = (float*)(ws + o_ald1);
    float* ard1 = (float*)(ws + o_ard1);
    float* ald2 = (float*)(ws + o_ald2);
    float* ard2 = (float*)(ws + o_ard2);

    int nscan = (N_NODES + 1 + 1023) / 1024;  // 99

    hipLaunchKernelGGL(detect_k, dim3(1), dim3(256), 0, stream, (const unsigned*)ei, flag);
    hipLaunchKernelGGL(init_k, dim3((N_NODES + 255) / 256), dim3(256), 0, stream, counts, fill);
    hipLaunchKernelGGL(count_k, dim3((N_EDGES + 255) / 256), dim3(256), 0, stream, ei, flag, counts);
    hipLaunchKernelGGL(scan1_k, dim3(nscan), dim3(256), 0, stream, counts, rowptr, bsums);
    hipLaunchKernelGGL(scan2_k, dim3(1), dim3(64), 0, stream, bsums, nscan);
    hipLaunchKernelGGL(scan3_k, dim3(nscan), dim3(256), 0, stream, rowptr, bsums);
    hipLaunchKernelGGL(scatter_k, dim3((EPRIME + 255) / 256), dim3(256), 0, stream,
                       ei, flag, rowptr, fill, col);
    hipLaunchKernelGGL(gemm1_k, dim3((N_NODES + 63) / 64), dim3(256), 0, stream,
                       x, W1, attl1, attr1, h1, ald1, ard1);
    hipLaunchKernelGGL(attn1_k, dim3((N_NODES + 3) / 4), dim3(256), 0, stream,
                       h1, rowptr, col, ald1, ard1, b1, hout);
    hipLaunchKernelGGL(gemm2_k, dim3((N_NODES + 31) / 32), dim3(256), 0, stream,
                       hout, W2, attl2, attr2, h2, ald2, ard2);
    hipLaunchKernelGGL(attn2_k, dim3((N_NODES + 3) / 4), dim3(256), 0, stream,
                       h2, rowptr, col, ald2, ard2, b2, out);
}